// Round 1
// baseline (3000.962 us; speedup 1.0000x reference)
//
#include <hip/hip_runtime.h>
#include <math.h>

#define BATCH 8
#define H 128
#define W 128
#define HW 16384

// ---------------------------------------------------------------------------
// Weight transpose: OIHW -> [I][KK][O]  (so conv staging reads are coalesced)
// ---------------------------------------------------------------------------
__global__ __launch_bounds__(256) void wtrans_kernel(
    const float* __restrict__ w, float* __restrict__ wt, int O, int I, int KK)
{
    int idx = blockIdx.x * 256 + threadIdx.x;
    int total = O * I * KK;
    if (idx >= total) return;
    int k = idx % KK;
    int rest = idx / KK;
    int i = rest % I;
    int o = rest / I;
    wt[(i * KK + k) * O + o] = w[idx];
}

// Combined weight for lam = sigmoid(lam_w . (fus_w2 . f) + b) = sigmoid(wc . f + b)
__global__ void wc_kernel(const float* __restrict__ fus_w2,
                          const float* __restrict__ lam_w,
                          float* __restrict__ wc)
{
    int ic = threadIdx.x;  // 128 threads
    float s = 0.f;
    for (int oc = 0; oc < 128; ++oc) s += lam_w[oc] * fus_w2[oc * 128 + ic];
    wc[ic] = s;
}

// ---------------------------------------------------------------------------
// Direct 3x3 conv, pad=1. Input = concat(in0[C0], in1[C1]) along channels.
// wt layout: [Cin][9][Cout]. Block: 32x4 pixels x 32 oc, 256 threads,
// each thread 4 px * 4 oc. LDS row stride 36 keeps ds_read_b128 aligned.
// ---------------------------------------------------------------------------
#define CK 8
__global__ __launch_bounds__(256) void conv3x3_kernel(
    const float* __restrict__ in0, int C0,
    const float* __restrict__ in1, int C1,
    const float* __restrict__ wt,
    const float* __restrict__ bias,   // may be null
    float* __restrict__ out, int Cout)
{
    __shared__ alignas(16) float s_in[CK][6][36];
    __shared__ alignas(16) float s_w[CK][9][32];

    int b = blockIdx.y;
    int octile = blockIdx.z * 32;
    int tile = blockIdx.x;             // 0..127
    int x0 = (tile & 3) * 32;
    int y0 = (tile >> 2) * 4;
    int tid = threadIdx.x;
    int oc4 = (tid & 7) * 4;           // 0,4,...,28
    int pg  = tid >> 3;                // 0..31
    int tyy = pg >> 3;                 // 0..3
    int txx = (pg & 7) * 4;            // 0..28
    int Cin = C0 + C1;

    float acc[4][4];
#pragma unroll
    for (int j = 0; j < 4; ++j)
#pragma unroll
        for (int o = 0; o < 4; ++o) acc[j][o] = 0.f;

    for (int cb = 0; cb < Cin; cb += CK) {
        __syncthreads();
        // stage input tile (6 rows x 34 cols per channel, zero-padded)
        for (int e = tid; e < CK * 6 * 34; e += 256) {
            int cc = e / 204;
            int rem = e - cc * 204;
            int r = rem / 34;
            int col = rem - r * 34;
            int gy = y0 + r - 1;
            int gx = x0 + col - 1;
            float v = 0.f;
            if (gy >= 0 && gy < H && gx >= 0 && gx < W) {
                int c = cb + cc;
                v = (c < C0) ? in0[((size_t)b * C0 + c) * HW + gy * W + gx]
                             : in1[((size_t)b * C1 + (c - C0)) * HW + gy * W + gx];
            }
            s_in[cc][r][col] = v;
        }
        // stage weights [cc][k][oc]
        for (int e = tid; e < CK * 9 * 32; e += 256) {
            int cc = e / 288;
            int rem = e - cc * 288;
            int k = rem / 32;
            int oc = rem - k * 32;
            int gc = octile + oc;
            s_w[cc][k][oc] = (gc < Cout) ? wt[((size_t)(cb + cc) * 9 + k) * Cout + gc] : 0.f;
        }
        __syncthreads();

#pragma unroll
        for (int cc = 0; cc < CK; ++cc) {
            float xin[3][6];
#pragma unroll
            for (int i = 0; i < 3; ++i) {
                const float4 v4 = *(const float4*)&s_in[cc][tyy + i][txx];
                const float2 v2 = *(const float2*)&s_in[cc][tyy + i][txx + 4];
                xin[i][0] = v4.x; xin[i][1] = v4.y; xin[i][2] = v4.z; xin[i][3] = v4.w;
                xin[i][4] = v2.x; xin[i][5] = v2.y;
            }
#pragma unroll
            for (int ky = 0; ky < 3; ++ky)
#pragma unroll
                for (int kx = 0; kx < 3; ++kx) {
                    const float4 wv = *(const float4*)&s_w[cc][ky * 3 + kx][oc4];
#pragma unroll
                    for (int j = 0; j < 4; ++j) {
                        float xv = xin[ky][j + kx];
                        acc[j][0] += wv.x * xv;
                        acc[j][1] += wv.y * xv;
                        acc[j][2] += wv.z * xv;
                        acc[j][3] += wv.w * xv;
                    }
                }
        }
    }

    int ox = x0 + txx;
    int oy = y0 + tyy;
#pragma unroll
    for (int o = 0; o < 4; ++o) {
        int oc = octile + oc4 + o;
        if (oc < Cout) {
            float bv = bias ? bias[oc] : 0.f;
            float4 vv = make_float4(acc[0][o] + bv, acc[1][o] + bv,
                                    acc[2][o] + bv, acc[3][o] + bv);
            *(float4*)&out[((size_t)b * Cout + oc) * HW + oy * W + ox] = vv;
        }
    }
}

// ---------------------------------------------------------------------------
// GroupNorm stats: one block per (b,g); group region is contiguous in NCHW.
// ---------------------------------------------------------------------------
__global__ __launch_bounds__(256) void gn_stats_kernel(
    const float* __restrict__ x, float* __restrict__ stats, int CgHW)
{
    int bg = blockIdx.x;  // B*32
    const float4* p4 = (const float4*)(x + (size_t)bg * CgHW);
    int n4 = CgHW / 4;
    float s1 = 0.f, s2 = 0.f;
    for (int i = threadIdx.x; i < n4; i += 256) {
        float4 v = p4[i];
        s1 += v.x + v.y + v.z + v.w;
        s2 += v.x * v.x + v.y * v.y + v.z * v.z + v.w * v.w;
    }
    for (int off = 32; off > 0; off >>= 1) {
        s1 += __shfl_down(s1, off);
        s2 += __shfl_down(s2, off);
    }
    __shared__ float r1[4], r2[4];
    int wid = threadIdx.x >> 6;
    if ((threadIdx.x & 63) == 0) { r1[wid] = s1; r2[wid] = s2; }
    __syncthreads();
    if (threadIdx.x == 0) {
        float a = r1[0] + r1[1] + r1[2] + r1[3];
        float q = r2[0] + r2[1] + r2[2] + r2[3];
        float inv_n = 1.0f / (float)CgHW;
        float mean = a * inv_n;
        float var = q * inv_n - mean * mean;
        stats[bg * 2] = mean;
        stats[bg * 2 + 1] = rsqrtf(var + 1e-5f);
    }
}

// act: 0 none, 1 silu, 2 relu
__global__ __launch_bounds__(256) void gn_norm_act_kernel(
    const float* __restrict__ x, float* __restrict__ y,
    const float* __restrict__ gamma, const float* __restrict__ beta,
    const float* __restrict__ stats, int C, int Cg, int act)
{
    int idx = blockIdx.x * 256 + threadIdx.x;  // float4 index
    int total4 = BATCH * C * HW / 4;
    if (idx >= total4) return;
    int e = idx * 4;
    int c = (e / HW) % C;
    int b = e / (C * HW);
    int g = c / Cg;
    float mean = stats[(b * 32 + g) * 2];
    float rstd = stats[(b * 32 + g) * 2 + 1];
    float sc = rstd * gamma[c];
    float sh = beta[c] - mean * sc;
    float4 v = ((const float4*)x)[idx];
    float r[4] = {v.x, v.y, v.z, v.w};
#pragma unroll
    for (int i = 0; i < 4; ++i) {
        float t = r[i] * sc + sh;
        if (act == 1) t = t / (1.f + expf(-t));
        else if (act == 2) t = fmaxf(t, 0.f);
        r[i] = t;
    }
    ((float4*)y)[idx] = make_float4(r[0], r[1], r[2], r[3]);
}

// ---------------------------------------------------------------------------
// Bilinear warp * sigmoid(validity); also writes flow output.
// ---------------------------------------------------------------------------
__global__ __launch_bounds__(256) void warp_kernel(
    const float* __restrict__ feat2, const float* __restrict__ pred,
    float* __restrict__ aligned, float* __restrict__ flow_out)
{
    int idx = blockIdx.x * 256 + threadIdx.x;  // pixel over B*HW
    int b = idx / HW;
    int p = idx - b * HW;
    int y = p >> 7;
    int x = p & 127;
    const float* predb = pred + (size_t)b * 3 * HW;
    float fx = predb[p];
    float fy = predb[HW + p];
    float validity = 1.f / (1.f + expf(-predb[2 * HW + p]));
    flow_out[(size_t)(b * 2) * HW + p] = fx;
    flow_out[(size_t)(b * 2 + 1) * HW + p] = fy;

    float px = (float)x + fx;
    float py = (float)y + fy;
    float x0f = floorf(px), y0f = floorf(py);
    float wx = px - x0f, wy = py - y0f;
    int xi0 = (int)x0f, yi0 = (int)y0f;
    float wgt[2][2] = {{(1.f - wx) * (1.f - wy), wx * (1.f - wy)},
                       {(1.f - wx) * wy,         wx * wy}};
    float vm[2][2];
    int offc[2][2];
#pragma unroll
    for (int yy = 0; yy < 2; ++yy)
#pragma unroll
        for (int xx = 0; xx < 2; ++xx) {
            int xi = xi0 + xx, yi = yi0 + yy;
            bool ok = (xi >= 0) && (xi <= W - 1) && (yi >= 0) && (yi <= H - 1);
            vm[yy][xx] = ok ? wgt[yy][xx] : 0.f;
            int xc = min(max(xi, 0), W - 1);
            int yc = min(max(yi, 0), H - 1);
            offc[yy][xx] = yc * W + xc;
        }
    const float* f2b = feat2 + (size_t)b * 128 * HW;
    float* outb = aligned + (size_t)b * 128 * HW;
    for (int c = 0; c < 128; ++c) {
        const float* f2c = f2b + (size_t)c * HW;
        float val = f2c[offc[0][0]] * vm[0][0] + f2c[offc[0][1]] * vm[0][1] +
                    f2c[offc[1][0]] * vm[1][0] + f2c[offc[1][1]] * vm[1][1];
        outb[(size_t)c * HW + p] = val * validity;
    }
}

// ---------------------------------------------------------------------------
// Cost volume: cv[b, dy*9+dx, y, x] = mean_c f1[c,y,x] * alignedPad[c,y+dy-4,x+dx-4]
// 16x16 pixel tile, 4-channel chunks packed innermost for ds_read_b128.
// ---------------------------------------------------------------------------
__global__ __launch_bounds__(256) void costvol_kernel(
    const float* __restrict__ feat1, const float* __restrict__ aligned,
    float* __restrict__ cv)
{
    __shared__ alignas(16) float s_al[24 * 24 * 4];
    int b = blockIdx.y;
    int bx = blockIdx.x & 7, by = blockIdx.x >> 3;
    int tid = threadIdx.x;
    int ly = tid >> 4, lx = tid & 15;
    int gy = by * 16 + ly, gx = bx * 16 + lx;

    float acc[81];
#pragma unroll
    for (int k = 0; k < 81; ++k) acc[k] = 0.f;

    const float* f1b = feat1 + (size_t)b * 128 * HW;
    const float* alb = aligned + (size_t)b * 128 * HW;

    for (int c0 = 0; c0 < 128; c0 += 4) {
        __syncthreads();
        for (int e = tid; e < 24 * 24 * 4; e += 256) {
            int cc = e / 576;
            int rem = e - cc * 576;
            int r = rem / 24;
            int col = rem - r * 24;
            int ay = by * 16 + r - 4, ax = bx * 16 + col - 4;
            float v = 0.f;
            if (ay >= 0 && ay < H && ax >= 0 && ax < W)
                v = alb[(size_t)(c0 + cc) * HW + ay * W + ax];
            s_al[(r * 24 + col) * 4 + cc] = v;
        }
        __syncthreads();
        float f1v[4];
#pragma unroll
        for (int cc = 0; cc < 4; ++cc)
            f1v[cc] = f1b[(size_t)(c0 + cc) * HW + gy * W + gx];
#pragma unroll
        for (int dy = 0; dy < 9; ++dy) {
#pragma unroll
            for (int dx = 0; dx < 9; ++dx) {
                const float4 av = *(const float4*)&s_al[((ly + dy) * 24 + lx + dx) * 4];
                acc[dy * 9 + dx] += av.x * f1v[0] + av.y * f1v[1] + av.z * f1v[2] + av.w * f1v[3];
            }
        }
    }
    const float scale = 1.f / 128.f;
    float* cvb = cv + (size_t)b * 81 * HW + gy * W + gx;
#pragma unroll
    for (int k = 0; k < 81; ++k) cvb[(size_t)k * HW] = acc[k] * scale;
}

// ---------------------------------------------------------------------------
// 1x1 conv, Cout=64. If inB != null: input = |inA - inB| (fused diff).
// wt layout [Cin][64].
// ---------------------------------------------------------------------------
__global__ __launch_bounds__(256) void conv1x1_kernel(
    const float* __restrict__ inA, const float* __restrict__ inB,
    const float* __restrict__ wt, float* __restrict__ out, int Cin)
{
    __shared__ alignas(16) float s_w[128 * 64];
    int tid = threadIdx.x;
    for (int e = tid; e < Cin * 64; e += 256) s_w[e] = wt[e];
    __syncthreads();
    int idx = blockIdx.x * 256 + tid;  // pixel over B*HW
    int b = idx / HW;
    int p = idx - b * HW;
    float acc[64];
#pragma unroll
    for (int o = 0; o < 64; ++o) acc[o] = 0.f;
    const float* Ab = inA + (size_t)b * Cin * HW + p;
    const float* Bb = inB ? inB + (size_t)b * Cin * HW + p : nullptr;
    for (int ic = 0; ic < Cin; ++ic) {
        float xv = Ab[(size_t)ic * HW];
        if (inB) xv = fabsf(xv - Bb[(size_t)ic * HW]);
        const float* wr = &s_w[ic * 64];
#pragma unroll
        for (int o4 = 0; o4 < 64; o4 += 4) {
            const float4 wv = *(const float4*)&wr[o4];
            acc[o4 + 0] += wv.x * xv;
            acc[o4 + 1] += wv.y * xv;
            acc[o4 + 2] += wv.z * xv;
            acc[o4 + 3] += wv.w * xv;
        }
    }
    float* ob = out + (size_t)b * 64 * HW + p;
#pragma unroll
    for (int o = 0; o < 64; ++o) ob[(size_t)o * HW] = acc[o];
}

// lam = sigmoid(wc . f1 + lam_b)
__global__ __launch_bounds__(256) void lam_kernel(
    const float* __restrict__ f1, const float* __restrict__ wc,
    const float* __restrict__ lam_b, float* __restrict__ out)
{
    __shared__ float s_w[128];
    int tid = threadIdx.x;
    if (tid < 128) s_w[tid] = wc[tid];
    __syncthreads();
    int idx = blockIdx.x * 256 + tid;
    int b = idx / HW;
    int p = idx - b * HW;
    const float* fb = f1 + (size_t)b * 128 * HW + p;
    float acc = 0.f;
#pragma unroll 4
    for (int ic = 0; ic < 128; ++ic) acc += s_w[ic] * fb[(size_t)ic * HW];
    acc += lam_b[0];
    out[idx] = 1.f / (1.f + expf(-acc));
}

// ---------------------------------------------------------------------------
extern "C" void kernel_launch(void* const* d_in, const int* in_sizes, int n_in,
                              void* d_out, int out_size, void* d_ws, size_t ws_size,
                              hipStream_t stream)
{
    const float* feat1     = (const float*)d_in[0];
    const float* feat2     = (const float*)d_in[1];
    const float* off_w1    = (const float*)d_in[2];
    const float* off_g1    = (const float*)d_in[3];
    const float* off_b1    = (const float*)d_in[4];
    const float* off_w2    = (const float*)d_in[5];
    const float* off_g2    = (const float*)d_in[6];
    const float* off_b2    = (const float*)d_in[7];
    const float* off_w3    = (const float*)d_in[8];
    const float* off_bias3 = (const float*)d_in[9];
    const float* corr_w    = (const float*)d_in[10];
    const float* corr_g    = (const float*)d_in[11];
    const float* corr_b    = (const float*)d_in[12];
    const float* diff_w    = (const float*)d_in[13];
    const float* diff_g    = (const float*)d_in[14];
    const float* diff_b    = (const float*)d_in[15];
    const float* fus_w1    = (const float*)d_in[16];
    const float* fus_g1    = (const float*)d_in[17];
    const float* fus_b1    = (const float*)d_in[18];
    const float* fus_w2    = (const float*)d_in[19];
    const float* lam_w     = (const float*)d_in[20];
    const float* lam_b     = (const float*)d_in[21];

    float* ws = (float*)d_ws;
    float* x1   = ws;                   // 16,777,216 (x1 then f1)
    float* x2   = ws + 16777216;        //  8,388,608 (x2 then de)
    float* cv   = ws + 25165824;        // 10,616,832
    float* ce   = ws + 35782656;        //  8,388,608
    float* pred = ws + 44171264;        //    393,216
    float* wT1  = ws + 44564480;        //    294,912
    float* wT2  = ws + 44859392;        //     73,728
    float* wT3  = ws + 44933120;        //      2,048
    float* wTf  = ws + 44935168;        //    147,456
    float* wTc  = ws + 45082624;        //      5,248
    float* wTd  = ws + 45087872;        //      8,192
    float* wcb  = ws + 45096064;        //        128
    float* st   = ws + 45096192;        //      2,560 (5 x 512)

    float* aligned  = (float*)d_out;
    float* flow_out = aligned + 16777216;
    float* lam_out  = aligned + 17039360;

    auto T = [&](const float* w, float* wt, int O, int I, int KK) {
        int total = O * I * KK;
        hipLaunchKernelGGL(wtrans_kernel, dim3((total + 255) / 256), dim3(256), 0, stream,
                           w, wt, O, I, KK);
    };
    T(off_w1, wT1, 128, 256, 9);
    T(off_w2, wT2, 64, 128, 9);
    T(off_w3, wT3, 3, 64, 9);
    T(fus_w1, wTf, 128, 128, 9);
    T(corr_w, wTc, 64, 81, 1);
    T(diff_w, wTd, 64, 128, 1);
    hipLaunchKernelGGL(wc_kernel, dim3(1), dim3(128), 0, stream, fus_w2, lam_w, wcb);

    // offset net
    hipLaunchKernelGGL(conv3x3_kernel, dim3(128, 8, 4), dim3(256), 0, stream,
                       feat1, 128, feat2, 128, wT1, (const float*)nullptr, x1, 128);
    hipLaunchKernelGGL(gn_stats_kernel, dim3(256), dim3(256), 0, stream, x1, st, 65536);
    hipLaunchKernelGGL(gn_norm_act_kernel, dim3(16384), dim3(256), 0, stream,
                       x1, x1, off_g1, off_b1, st, 128, 4, 1);
    hipLaunchKernelGGL(conv3x3_kernel, dim3(128, 8, 2), dim3(256), 0, stream,
                       x1, 128, (const float*)nullptr, 0, wT2, (const float*)nullptr, x2, 64);
    hipLaunchKernelGGL(gn_stats_kernel, dim3(256), dim3(256), 0, stream, x2, st + 512, 32768);
    hipLaunchKernelGGL(gn_norm_act_kernel, dim3(8192), dim3(256), 0, stream,
                       x2, x2, off_g2, off_b2, st + 512, 64, 2, 1);
    hipLaunchKernelGGL(conv3x3_kernel, dim3(128, 8, 1), dim3(256), 0, stream,
                       x2, 64, (const float*)nullptr, 0, wT3, off_bias3, pred, 3);

    // warp (writes aligned + flow outputs)
    hipLaunchKernelGGL(warp_kernel, dim3(512), dim3(256), 0, stream,
                       feat2, pred, aligned, flow_out);

    // cost volume
    hipLaunchKernelGGL(costvol_kernel, dim3(64, 8), dim3(256), 0, stream,
                       feat1, aligned, cv);

    // corr branch: 1x1 conv + GN + relu
    hipLaunchKernelGGL(conv1x1_kernel, dim3(512), dim3(256), 0, stream,
                       cv, (const float*)nullptr, wTc, ce, 81);
    hipLaunchKernelGGL(gn_stats_kernel, dim3(256), dim3(256), 0, stream, ce, st + 1024, 32768);
    hipLaunchKernelGGL(gn_norm_act_kernel, dim3(8192), dim3(256), 0, stream,
                       ce, ce, corr_g, corr_b, st + 1024, 64, 2, 2);

    // diff branch: fused |f1 - aligned| 1x1 conv + GN + relu (de lives in x2)
    hipLaunchKernelGGL(conv1x1_kernel, dim3(512), dim3(256), 0, stream,
                       feat1, aligned, wTd, x2, 128);
    hipLaunchKernelGGL(gn_stats_kernel, dim3(256), dim3(256), 0, stream, x2, st + 1536, 32768);
    hipLaunchKernelGGL(gn_norm_act_kernel, dim3(8192), dim3(256), 0, stream,
                       x2, x2, diff_g, diff_b, st + 1536, 64, 2, 2);

    // fusion conv 3x3 (concat ce,de) + GN + relu (f1 lives in x1)
    hipLaunchKernelGGL(conv3x3_kernel, dim3(128, 8, 4), dim3(256), 0, stream,
                       ce, 64, x2, 64, wTf, (const float*)nullptr, x1, 128);
    hipLaunchKernelGGL(gn_stats_kernel, dim3(256), dim3(256), 0, stream, x1, st + 2048, 65536);
    hipLaunchKernelGGL(gn_norm_act_kernel, dim3(16384), dim3(256), 0, stream,
                       x1, x1, fus_g1, fus_b1, st + 2048, 128, 4, 2);

    // lam (fus_w2 and lam_w folded into wc)
    hipLaunchKernelGGL(lam_kernel, dim3(512), dim3(256), 0, stream,
                       x1, wcb, lam_b, lam_out);
}

// Round 2
// 1095.777 us; speedup vs baseline: 2.7387x; 2.7387x over previous
//
#include <hip/hip_runtime.h>
#include <math.h>

#define BATCH 8
#define H 128
#define W 128
#define HW 16384

typedef short bf16x8 __attribute__((ext_vector_type(8)));
typedef float f32x16 __attribute__((ext_vector_type(16)));
typedef unsigned int u32;
typedef unsigned short u16;

__device__ __forceinline__ u16 f2bf(float v) {
    u32 u = __float_as_uint(v);
    u = (u + 0x7fffu + ((u >> 16) & 1u)) >> 16;
    return (u16)u;
}

__device__ __forceinline__ void async16(void* lds, const void* g) {
    __builtin_amdgcn_global_load_lds(
        (const __attribute__((address_space(1))) u32*)g,
        (__attribute__((address_space(3))) u32*)lds, 16, 0, 0);
}

// ---------------------------------------------------------------------------
// Weight transpose: OIHW -> [I][KK][O]   (for the small fp32 direct convs)
// ---------------------------------------------------------------------------
__global__ __launch_bounds__(256) void wtrans_kernel(
    const float* __restrict__ w, float* __restrict__ wt, int O, int I, int KK)
{
    int idx = blockIdx.x * 256 + threadIdx.x;
    int total = O * I * KK;
    if (idx >= total) return;
    int k = idx % KK;
    int rest = idx / KK;
    int i = rest % I;
    int o = rest / I;
    wt[(i * KK + k) * O + o] = w[idx];
}

__global__ void wc_kernel(const float* __restrict__ fus_w2,
                          const float* __restrict__ lam_w,
                          float* __restrict__ wc)
{
    int ic = threadIdx.x;
    float s = 0.f;
    for (int oc = 0; oc < 128; ++oc) s += lam_w[oc] * fus_w2[oc * 128 + ic];
    wc[ic] = s;
}

// ---------------------------------------------------------------------------
// MFMA weight prep: OIHW fp32 -> bf16 [icblk][ocblk][half][kidx][oc64][ic8]
// (exact LDS staging linear order; 9216 elems per (icblk,ocblk))
// ---------------------------------------------------------------------------
__global__ __launch_bounds__(256) void wprep_kernel(
    const float* __restrict__ w, u16* __restrict__ out, int Cin, int Cout)
{
    int idx = blockIdx.x * 256 + threadIdx.x;
    int total = Cin * 9 * Cout;
    if (idx >= total) return;
    int ocblks = Cout >> 6;
    int pair = idx / 9216;
    int r = idx - pair * 9216;
    int half = r / 4608;
    int r2 = r - half * 4608;
    int kidx = r2 / 512;
    int r3 = r2 - kidx * 512;
    int oc = r3 >> 3;
    int ic8 = r3 & 7;
    int icblk = pair / ocblks;
    int ocblk = pair - icblk * ocblks;
    int ic = icblk * 16 + half * 8 + ic8;
    int o = ocblk * 64 + oc;
    int ky = kidx / 3, kx = kidx - ky * 3;
    out[idx] = f2bf(w[((size_t)(o * Cin + ic) * 3 + ky) * 3 + kx]);
}

// ---------------------------------------------------------------------------
// concat(feat1,feat2) fp32 NCHW -> padded NHWC bf16 [B][130][130][256]
// ---------------------------------------------------------------------------
__global__ __launch_bounds__(256) void nhwc_concat_kernel(
    const float* __restrict__ f1, const float* __restrict__ f2,
    u16* __restrict__ out)
{
    __shared__ u16 s[32 * 256];
    int tid = threadIdx.x;
    int b = blockIdx.y;
    int xt = blockIdx.x & 3;
    int y = blockIdx.x >> 2;
    int x0 = xt * 32;
    for (int e = tid; e < 8192; e += 256) {
        int c = e >> 5, px = e & 31;
        const float* src = (c < 128) ? f1 + ((size_t)(b * 128 + c)) * HW
                                     : f2 + ((size_t)(b * 128 + c - 128)) * HW;
        s[px * 256 + c] = f2bf(src[y * W + x0 + px]);
    }
    __syncthreads();
    uint4* o4 = (uint4*)(out + (((size_t)b * 130 + y + 1) * 130 + x0 + 1) * 256);
    const uint4* s4 = (const uint4*)s;
    for (int e = tid; e < 1024; e += 256) o4[e] = s4[e];
}

// ---------------------------------------------------------------------------
// GN + act, fp32 NCHW -> padded NHWC bf16 (channel offset for concat targets)
// ---------------------------------------------------------------------------
__global__ __launch_bounds__(256) void gn_nhwc_kernel(
    const float* __restrict__ x, const float* __restrict__ gamma,
    const float* __restrict__ beta, const float* __restrict__ stats,
    u16* __restrict__ out, int Csrc, int Cdst, int coff, int Cg, int act)
{
    __shared__ u16 s[32 * 128];
    int tid = threadIdx.x;
    int b = blockIdx.y;
    int xt = blockIdx.x & 3;
    int y = blockIdx.x >> 2;
    int x0 = xt * 32;
    int n = 32 * Csrc;
    for (int e = tid; e < n; e += 256) {
        int c = e >> 5, px = e & 31;
        float v = x[((size_t)(b * Csrc + c)) * HW + y * W + x0 + px];
        int g = c / Cg;
        float mean = stats[(b * 32 + g) * 2];
        float rstd = stats[(b * 32 + g) * 2 + 1];
        float t = (v - mean) * rstd * gamma[c] + beta[c];
        t = (act == 1) ? t / (1.f + expf(-t)) : fmaxf(t, 0.f);
        s[px * Csrc + c] = f2bf(t);
    }
    __syncthreads();
    int cpp = Csrc >> 3;                 // uint4 chunks per pixel
    int chunks = 32 * cpp;
    for (int e = tid; e < chunks; e += 256) {
        int px = e / cpp, g = e - px * cpp;
        uint4 v = *(const uint4*)&s[px * Csrc + g * 8];
        *(uint4*)&out[(((size_t)b * 130 + y + 1) * 130 + x0 + 1 + px) * Cdst + coff + g * 8] = v;
    }
}

// ---------------------------------------------------------------------------
// MFMA implicit-GEMM 3x3 conv, pad=1.
// in: padded NHWC bf16 [B][130][130][Cin]; wprep: packed bf16; out: fp32 NCHW.
// Block: 256px (32w x 8h) x 64oc, 4 waves M-split; wave = 64px x 64oc.
// ---------------------------------------------------------------------------
__global__ __launch_bounds__(256, 2) void conv3x3_mfma_kernel(
    const u16* __restrict__ in_nhwc, const u16* __restrict__ wprep,
    float* __restrict__ out, int Cin, int Cout)
{
    __shared__ u16 s_in[2 * 10 * 34 * 8];   // [half][row10][col34][ic8] 10880B
    __shared__ u16 s_w[2 * 9 * 64 * 8];     // [half][kidx9][oc64][ic8] 18432B

    const int tid = threadIdx.x;
    const int b = blockIdx.y;
    const int x0 = (blockIdx.x & 3) * 32;
    const int y0 = (blockIdx.x >> 2) * 8;
    const int oc0 = blockIdx.z * 64;
    const int ocblks = Cout >> 6;
    const int icblks = Cin >> 4;

    const int lane = tid & 63;
    const int wv = tid >> 6;      // wave 0..3 -> rows wv*2, wv*2+1
    const int m = lane & 31;
    const int hh = lane >> 5;

    f32x16 acc[2][2];
#pragma unroll
    for (int t = 0; t < 2; ++t)
#pragma unroll
        for (int nt = 0; nt < 2; ++nt)
#pragma unroll
            for (int k = 0; k < 16; ++k) acc[t][nt][k] = 0.f;

    const u16* wsrc0 = wprep + (size_t)blockIdx.z * 9216;

    for (int it = 0; it < icblks; ++it) {
        const int ic0 = it * 16;
        __syncthreads();
        // stage input: 680 chunks of 16B -> [half][r][col][8]
        for (int e = tid; e < 680; e += 256) {
            int half = (e >= 340);
            int p = e - half * 340;
            int r = p / 34;
            int col = p - r * 34;
            const u16* src = in_nhwc +
                (((size_t)(b * 130 + y0 + r)) * 130 + (x0 + col)) * Cin + ic0 + half * 8;
            async16(&s_in[e * 8], src);
        }
        // stage weights: 1152 chunks of 16B
        const u16* wsrc = wsrc0 + (size_t)it * ocblks * 9216;
        for (int e = tid; e < 1152; e += 256)
            async16(&s_w[e * 8], wsrc + e * 8);
        __syncthreads();

#pragma unroll
        for (int kidx = 0; kidx < 9; ++kidx) {
            const int dy = kidx / 3, dx = kidx - dy * 3;
            bf16x8 a0 = *(const bf16x8*)&s_in[(hh * 340 + (wv * 2 + 0 + dy) * 34 + m + dx) * 8];
            bf16x8 a1 = *(const bf16x8*)&s_in[(hh * 340 + (wv * 2 + 1 + dy) * 34 + m + dx) * 8];
            bf16x8 b0 = *(const bf16x8*)&s_w[(hh * 576 + kidx * 64 + m) * 8];
            bf16x8 b1 = *(const bf16x8*)&s_w[(hh * 576 + kidx * 64 + 32 + m) * 8];
            acc[0][0] = __builtin_amdgcn_mfma_f32_32x32x16_bf16(a0, b0, acc[0][0], 0, 0, 0);
            acc[0][1] = __builtin_amdgcn_mfma_f32_32x32x16_bf16(a0, b1, acc[0][1], 0, 0, 0);
            acc[1][0] = __builtin_amdgcn_mfma_f32_32x32x16_bf16(a1, b0, acc[1][0], 0, 0, 0);
            acc[1][1] = __builtin_amdgcn_mfma_f32_32x32x16_bf16(a1, b1, acc[1][1], 0, 0, 0);
        }
    }

    // epilogue: D row = (reg&3) + 8*(reg>>2) + 4*h (x offset), col = oc
#pragma unroll
    for (int t = 0; t < 2; ++t) {
        int y = y0 + wv * 2 + t;
#pragma unroll
        for (int nt = 0; nt < 2; ++nt) {
            int oc = oc0 + nt * 32 + m;
            float* op = out + ((size_t)(b * Cout + oc)) * HW + y * W + x0;
#pragma unroll
            for (int g = 0; g < 4; ++g) {
                float4 v = make_float4(acc[t][nt][g * 4 + 0], acc[t][nt][g * 4 + 1],
                                       acc[t][nt][g * 4 + 2], acc[t][nt][g * 4 + 3]);
                *(float4*)(op + g * 8 + hh * 4) = v;
            }
        }
    }
}

// ---------------------------------------------------------------------------
// Direct fp32 3x3 conv (kept for tiny conv3: Cout=3)
// ---------------------------------------------------------------------------
#define CK 8
__global__ __launch_bounds__(256) void conv3x3_kernel(
    const float* __restrict__ in0, int C0,
    const float* __restrict__ in1, int C1,
    const float* __restrict__ wt,
    const float* __restrict__ bias,
    float* __restrict__ out, int Cout)
{
    __shared__ alignas(16) float s_in[CK][6][36];
    __shared__ alignas(16) float s_w[CK][9][32];

    int b = blockIdx.y;
    int octile = blockIdx.z * 32;
    int tile = blockIdx.x;
    int x0 = (tile & 3) * 32;
    int y0 = (tile >> 2) * 4;
    int tid = threadIdx.x;
    int oc4 = (tid & 7) * 4;
    int pg = tid >> 3;
    int tyy = pg >> 3;
    int txx = (pg & 7) * 4;
    int Cin = C0 + C1;

    float acc[4][4];
#pragma unroll
    for (int j = 0; j < 4; ++j)
#pragma unroll
        for (int o = 0; o < 4; ++o) acc[j][o] = 0.f;

    for (int cb = 0; cb < Cin; cb += CK) {
        __syncthreads();
        for (int e = tid; e < CK * 6 * 34; e += 256) {
            int cc = e / 204;
            int rem = e - cc * 204;
            int r = rem / 34;
            int col = rem - r * 34;
            int gy = y0 + r - 1;
            int gx = x0 + col - 1;
            float v = 0.f;
            if (gy >= 0 && gy < H && gx >= 0 && gx < W) {
                int c = cb + cc;
                v = (c < C0) ? in0[((size_t)b * C0 + c) * HW + gy * W + gx]
                             : in1[((size_t)b * C1 + (c - C0)) * HW + gy * W + gx];
            }
            s_in[cc][r][col] = v;
        }
        for (int e = tid; e < CK * 9 * 32; e += 256) {
            int cc = e / 288;
            int rem = e - cc * 288;
            int k = rem / 32;
            int oc = rem - k * 32;
            int gc = octile + oc;
            s_w[cc][k][oc] = (gc < Cout) ? wt[((size_t)(cb + cc) * 9 + k) * Cout + gc] : 0.f;
        }
        __syncthreads();

#pragma unroll
        for (int cc = 0; cc < CK; ++cc) {
            float xin[3][6];
#pragma unroll
            for (int i = 0; i < 3; ++i) {
                const float4 v4 = *(const float4*)&s_in[cc][tyy + i][txx];
                const float2 v2 = *(const float2*)&s_in[cc][tyy + i][txx + 4];
                xin[i][0] = v4.x; xin[i][1] = v4.y; xin[i][2] = v4.z; xin[i][3] = v4.w;
                xin[i][4] = v2.x; xin[i][5] = v2.y;
            }
#pragma unroll
            for (int ky = 0; ky < 3; ++ky)
#pragma unroll
                for (int kx = 0; kx < 3; ++kx) {
                    const float4 wvv = *(const float4*)&s_w[cc][ky * 3 + kx][oc4];
#pragma unroll
                    for (int j = 0; j < 4; ++j) {
                        float xv = xin[ky][j + kx];
                        acc[j][0] += wvv.x * xv;
                        acc[j][1] += wvv.y * xv;
                        acc[j][2] += wvv.z * xv;
                        acc[j][3] += wvv.w * xv;
                    }
                }
        }
    }

    int ox = x0 + txx;
    int oy = y0 + tyy;
#pragma unroll
    for (int o = 0; o < 4; ++o) {
        int oc = octile + oc4 + o;
        if (oc < Cout) {
            float bv = bias ? bias[oc] : 0.f;
            float4 vv = make_float4(acc[0][o] + bv, acc[1][o] + bv,
                                    acc[2][o] + bv, acc[3][o] + bv);
            *(float4*)&out[((size_t)b * Cout + oc) * HW + oy * W + ox] = vv;
        }
    }
}

// ---------------------------------------------------------------------------
__global__ __launch_bounds__(256) void gn_stats_kernel(
    const float* __restrict__ x, float* __restrict__ stats, int CgHW)
{
    int bg = blockIdx.x;
    const float4* p4 = (const float4*)(x + (size_t)bg * CgHW);
    int n4 = CgHW / 4;
    float s1 = 0.f, s2 = 0.f;
    for (int i = threadIdx.x; i < n4; i += 256) {
        float4 v = p4[i];
        s1 += v.x + v.y + v.z + v.w;
        s2 += v.x * v.x + v.y * v.y + v.z * v.z + v.w * v.w;
    }
    for (int off = 32; off > 0; off >>= 1) {
        s1 += __shfl_down(s1, off);
        s2 += __shfl_down(s2, off);
    }
    __shared__ float r1[4], r2[4];
    int wid = threadIdx.x >> 6;
    if ((threadIdx.x & 63) == 0) { r1[wid] = s1; r2[wid] = s2; }
    __syncthreads();
    if (threadIdx.x == 0) {
        float a = r1[0] + r1[1] + r1[2] + r1[3];
        float q = r2[0] + r2[1] + r2[2] + r2[3];
        float inv_n = 1.0f / (float)CgHW;
        float mean = a * inv_n;
        float var = q * inv_n - mean * mean;
        stats[bg * 2] = mean;
        stats[bg * 2 + 1] = rsqrtf(var + 1e-5f);
    }
}

__global__ __launch_bounds__(256) void gn_norm_act_kernel(
    const float* __restrict__ x, float* __restrict__ y,
    const float* __restrict__ gamma, const float* __restrict__ beta,
    const float* __restrict__ stats, int C, int Cg, int act)
{
    int idx = blockIdx.x * 256 + threadIdx.x;
    int total4 = BATCH * C * HW / 4;
    if (idx >= total4) return;
    int e = idx * 4;
    int c = (e / HW) % C;
    int b = e / (C * HW);
    int g = c / Cg;
    float mean = stats[(b * 32 + g) * 2];
    float rstd = stats[(b * 32 + g) * 2 + 1];
    float sc = rstd * gamma[c];
    float sh = beta[c] - mean * sc;
    float4 v = ((const float4*)x)[idx];
    float r[4] = {v.x, v.y, v.z, v.w};
#pragma unroll
    for (int i = 0; i < 4; ++i) {
        float t = r[i] * sc + sh;
        if (act == 1) t = t / (1.f + expf(-t));
        else if (act == 2) t = fmaxf(t, 0.f);
        r[i] = t;
    }
    ((float4*)y)[idx] = make_float4(r[0], r[1], r[2], r[3]);
}

// ---------------------------------------------------------------------------
__global__ __launch_bounds__(256) void warp_kernel(
    const float* __restrict__ feat2, const float* __restrict__ pred,
    float* __restrict__ aligned, float* __restrict__ flow_out)
{
    int idx = blockIdx.x * 256 + threadIdx.x;
    int b = idx / HW;
    int p = idx - b * HW;
    int y = p >> 7;
    int x = p & 127;
    const float* predb = pred + (size_t)b * 3 * HW;
    float fx = predb[p];
    float fy = predb[HW + p];
    float validity = 1.f / (1.f + expf(-predb[2 * HW + p]));
    flow_out[(size_t)(b * 2) * HW + p] = fx;
    flow_out[(size_t)(b * 2 + 1) * HW + p] = fy;

    float px = (float)x + fx;
    float py = (float)y + fy;
    float x0f = floorf(px), y0f = floorf(py);
    float wx = px - x0f, wy = py - y0f;
    int xi0 = (int)x0f, yi0 = (int)y0f;
    float wgt[2][2] = {{(1.f - wx) * (1.f - wy), wx * (1.f - wy)},
                       {(1.f - wx) * wy, wx * wy}};
    float vm[2][2];
    int offc[2][2];
#pragma unroll
    for (int yy = 0; yy < 2; ++yy)
#pragma unroll
        for (int xx = 0; xx < 2; ++xx) {
            int xi = xi0 + xx, yi = yi0 + yy;
            bool ok = (xi >= 0) && (xi <= W - 1) && (yi >= 0) && (yi <= H - 1);
            vm[yy][xx] = ok ? wgt[yy][xx] : 0.f;
            int xc = min(max(xi, 0), W - 1);
            int yc = min(max(yi, 0), H - 1);
            offc[yy][xx] = yc * W + xc;
        }
    const float* f2b = feat2 + (size_t)b * 128 * HW;
    float* outb = aligned + (size_t)b * 128 * HW;
    for (int c = 0; c < 128; ++c) {
        const float* f2c = f2b + (size_t)c * HW;
        float val = f2c[offc[0][0]] * vm[0][0] + f2c[offc[0][1]] * vm[0][1] +
                    f2c[offc[1][0]] * vm[1][0] + f2c[offc[1][1]] * vm[1][1];
        outb[(size_t)c * HW + p] = val * validity;
    }
}

// ---------------------------------------------------------------------------
__global__ __launch_bounds__(256) void costvol_kernel(
    const float* __restrict__ feat1, const float* __restrict__ aligned,
    float* __restrict__ cv)
{
    __shared__ alignas(16) float s_al[24 * 24 * 4];
    int b = blockIdx.y;
    int bx = blockIdx.x & 7, by = blockIdx.x >> 3;
    int tid = threadIdx.x;
    int ly = tid >> 4, lx = tid & 15;
    int gy = by * 16 + ly, gx = bx * 16 + lx;

    float acc[81];
#pragma unroll
    for (int k = 0; k < 81; ++k) acc[k] = 0.f;

    const float* f1b = feat1 + (size_t)b * 128 * HW;
    const float* alb = aligned + (size_t)b * 128 * HW;

    for (int c0 = 0; c0 < 128; c0 += 4) {
        __syncthreads();
        for (int e = tid; e < 24 * 24 * 4; e += 256) {
            int cc = e / 576;
            int rem = e - cc * 576;
            int r = rem / 24;
            int col = rem - r * 24;
            int ay = by * 16 + r - 4, ax = bx * 16 + col - 4;
            float v = 0.f;
            if (ay >= 0 && ay < H && ax >= 0 && ax < W)
                v = alb[(size_t)(c0 + cc) * HW + ay * W + ax];
            s_al[(r * 24 + col) * 4 + cc] = v;
        }
        __syncthreads();
        float f1v[4];
#pragma unroll
        for (int cc = 0; cc < 4; ++cc)
            f1v[cc] = f1b[(size_t)(c0 + cc) * HW + gy * W + gx];
#pragma unroll
        for (int dy = 0; dy < 9; ++dy) {
#pragma unroll
            for (int dx = 0; dx < 9; ++dx) {
                const float4 av = *(const float4*)&s_al[((ly + dy) * 24 + lx + dx) * 4];
                acc[dy * 9 + dx] += av.x * f1v[0] + av.y * f1v[1] + av.z * f1v[2] + av.w * f1v[3];
            }
        }
    }
    const float scale = 1.f / 128.f;
    float* cvb = cv + (size_t)b * 81 * HW + gy * W + gx;
#pragma unroll
    for (int k = 0; k < 81; ++k) cvb[(size_t)k * HW] = acc[k] * scale;
}

// ---------------------------------------------------------------------------
__global__ __launch_bounds__(256) void conv1x1_kernel(
    const float* __restrict__ inA, const float* __restrict__ inB,
    const float* __restrict__ wt, float* __restrict__ out, int Cin)
{
    __shared__ alignas(16) float s_w[128 * 64];
    int tid = threadIdx.x;
    for (int e = tid; e < Cin * 64; e += 256) s_w[e] = wt[e];
    __syncthreads();
    int idx = blockIdx.x * 256 + tid;
    int b = idx / HW;
    int p = idx - b * HW;
    float acc[64];
#pragma unroll
    for (int o = 0; o < 64; ++o) acc[o] = 0.f;
    const float* Ab = inA + (size_t)b * Cin * HW + p;
    const float* Bb = inB ? inB + (size_t)b * Cin * HW + p : nullptr;
    for (int ic = 0; ic < Cin; ++ic) {
        float xv = Ab[(size_t)ic * HW];
        if (inB) xv = fabsf(xv - Bb[(size_t)ic * HW]);
        const float* wr = &s_w[ic * 64];
#pragma unroll
        for (int o4 = 0; o4 < 64; o4 += 4) {
            const float4 wvv = *(const float4*)&wr[o4];
            acc[o4 + 0] += wvv.x * xv;
            acc[o4 + 1] += wvv.y * xv;
            acc[o4 + 2] += wvv.z * xv;
            acc[o4 + 3] += wvv.w * xv;
        }
    }
    float* ob = out + (size_t)b * 64 * HW + p;
#pragma unroll
    for (int o = 0; o < 64; ++o) ob[(size_t)o * HW] = acc[o];
}

__global__ __launch_bounds__(256) void lam_kernel(
    const float* __restrict__ f1, const float* __restrict__ wc,
    const float* __restrict__ lam_b, float* __restrict__ out)
{
    __shared__ float s_w[128];
    int tid = threadIdx.x;
    if (tid < 128) s_w[tid] = wc[tid];
    __syncthreads();
    int idx = blockIdx.x * 256 + tid;
    int b = idx / HW;
    int p = idx - b * HW;
    const float* fb = f1 + (size_t)b * 128 * HW + p;
    float acc = 0.f;
#pragma unroll 4
    for (int ic = 0; ic < 128; ++ic) acc += s_w[ic] * fb[(size_t)ic * HW];
    acc += lam_b[0];
    out[idx] = 1.f / (1.f + expf(-acc));
}

// ---------------------------------------------------------------------------
extern "C" void kernel_launch(void* const* d_in, const int* in_sizes, int n_in,
                              void* d_out, int out_size, void* d_ws, size_t ws_size,
                              hipStream_t stream)
{
    const float* feat1     = (const float*)d_in[0];
    const float* feat2     = (const float*)d_in[1];
    const float* off_w1    = (const float*)d_in[2];
    const float* off_g1    = (const float*)d_in[3];
    const float* off_b1    = (const float*)d_in[4];
    const float* off_w2    = (const float*)d_in[5];
    const float* off_g2    = (const float*)d_in[6];
    const float* off_b2    = (const float*)d_in[7];
    const float* off_w3    = (const float*)d_in[8];
    const float* off_bias3 = (const float*)d_in[9];
    const float* corr_w    = (const float*)d_in[10];
    const float* corr_g    = (const float*)d_in[11];
    const float* corr_b    = (const float*)d_in[12];
    const float* diff_w    = (const float*)d_in[13];
    const float* diff_g    = (const float*)d_in[14];
    const float* diff_b    = (const float*)d_in[15];
    const float* fus_w1    = (const float*)d_in[16];
    const float* fus_g1    = (const float*)d_in[17];
    const float* fus_b1    = (const float*)d_in[18];
    const float* fus_w2    = (const float*)d_in[19];
    const float* lam_w     = (const float*)d_in[20];
    const float* lam_b     = (const float*)d_in[21];

    float* ws = (float*)d_ws;
    // region map (floats):
    float* x1  = ws;                      // 16,777,216  conv1 out / fus1 out
    float* x2  = ws + 16777216;           //  8,388,608  conv2 out / de
    float* Rcv = ws + 25165824;           // 10,616,832  p2 -> cv -> pf
    float* Rp1 = ws + 35782656;           // 17,305,600  p1 -> (ce, pred)
    u16*  wp1u = (u16*)(ws + 53088256);   //   294,912 u16
    u16*  wp2u = (u16*)(ws + 53235712);   //    73,728 u16
    u16*  wpfu = (u16*)(ws + 53272576);   //   147,456 u16
    float* wT3 = ws + 53346304;           //     1,728
    float* wTc = ws + 53348032;           //     5,184
    float* wTd = ws + 53353216;           //     8,192
    float* wcb = ws + 53361408;           //       128
    float* st  = ws + 53361536;           //     2,560

    u16* p1u = (u16*)Rp1;                 // [8][130][130][256] bf16
    u16* p2u = (u16*)Rcv;                 // [8][130][130][128] bf16
    u16* pfu = (u16*)Rcv;                 // [8][130][130][128] bf16 (after cv dead)
    float* cv = Rcv;
    float* ce = Rp1;                      // after p1 dead
    float* pred = Rp1 + 8388608;          // after p1 dead

    float* aligned  = (float*)d_out;
    float* flow_out = aligned + 16777216;
    float* lam_out  = aligned + 17039360;

    // ---- weight prep ----
    auto T = [&](const float* w, float* wt, int O, int I, int KK) {
        int total = O * I * KK;
        hipLaunchKernelGGL(wtrans_kernel, dim3((total + 255) / 256), dim3(256), 0, stream,
                           w, wt, O, I, KK);
    };
    T(off_w3, wT3, 3, 64, 9);
    T(corr_w, wTc, 64, 81, 1);
    T(diff_w, wTd, 64, 128, 1);
    hipLaunchKernelGGL(wc_kernel, dim3(1), dim3(128), 0, stream, fus_w2, lam_w, wcb);
    hipLaunchKernelGGL(wprep_kernel, dim3(1152), dim3(256), 0, stream, off_w1, wp1u, 256, 128);
    hipLaunchKernelGGL(wprep_kernel, dim3(288), dim3(256), 0, stream, off_w2, wp2u, 128, 64);
    hipLaunchKernelGGL(wprep_kernel, dim3(576), dim3(256), 0, stream, fus_w1, wpfu, 128, 128);

    // zero padded NHWC buffers (borders)
    hipMemsetAsync(p1u, 0, (size_t)34611200 * 2, stream);
    hipMemsetAsync(p2u, 0, (size_t)17305600 * 2, stream);

    // ---- offset net ----
    hipLaunchKernelGGL(nhwc_concat_kernel, dim3(512, 8), dim3(256), 0, stream,
                       feat1, feat2, p1u);
    hipLaunchKernelGGL(conv3x3_mfma_kernel, dim3(64, 8, 2), dim3(256), 0, stream,
                       p1u, wp1u, x1, 256, 128);
    hipLaunchKernelGGL(gn_stats_kernel, dim3(256), dim3(256), 0, stream, x1, st, 65536);
    hipLaunchKernelGGL(gn_nhwc_kernel, dim3(512, 8), dim3(256), 0, stream,
                       x1, off_g1, off_b1, st, p2u, 128, 128, 0, 4, 1);
    hipLaunchKernelGGL(conv3x3_mfma_kernel, dim3(64, 8, 1), dim3(256), 0, stream,
                       p2u, wp2u, x2, 128, 64);
    hipLaunchKernelGGL(gn_stats_kernel, dim3(256), dim3(256), 0, stream, x2, st + 512, 32768);
    hipLaunchKernelGGL(gn_norm_act_kernel, dim3(8192), dim3(256), 0, stream,
                       x2, x2, off_g2, off_b2, st + 512, 64, 2, 1);
    hipLaunchKernelGGL(conv3x3_kernel, dim3(128, 8, 1), dim3(256), 0, stream,
                       x2, 64, (const float*)nullptr, 0, wT3, off_bias3, pred, 3);

    // ---- warp + cost volume ----
    hipLaunchKernelGGL(warp_kernel, dim3(512), dim3(256), 0, stream,
                       feat2, pred, aligned, flow_out);
    hipLaunchKernelGGL(costvol_kernel, dim3(64, 8), dim3(256), 0, stream,
                       feat1, aligned, cv);

    // ---- corr branch ----
    hipLaunchKernelGGL(conv1x1_kernel, dim3(512), dim3(256), 0, stream,
                       cv, (const float*)nullptr, wTc, ce, 81);
    hipLaunchKernelGGL(gn_stats_kernel, dim3(256), dim3(256), 0, stream, ce, st + 1024, 32768);
    hipMemsetAsync(pfu, 0, (size_t)17305600 * 2, stream);   // cv dead; re-zero pf borders
    hipLaunchKernelGGL(gn_nhwc_kernel, dim3(512, 8), dim3(256), 0, stream,
                       ce, corr_g, corr_b, st + 1024, pfu, 64, 128, 0, 2, 2);

    // ---- diff branch (de in x2) ----
    hipLaunchKernelGGL(conv1x1_kernel, dim3(512), dim3(256), 0, stream,
                       feat1, aligned, wTd, x2, 128);
    hipLaunchKernelGGL(gn_stats_kernel, dim3(256), dim3(256), 0, stream, x2, st + 1536, 32768);
    hipLaunchKernelGGL(gn_nhwc_kernel, dim3(512, 8), dim3(256), 0, stream,
                       x2, diff_g, diff_b, st + 1536, pfu, 64, 128, 64, 2, 2);

    // ---- fusion ----
    hipLaunchKernelGGL(conv3x3_mfma_kernel, dim3(64, 8, 2), dim3(256), 0, stream,
                       pfu, wpfu, x1, 128, 128);
    hipLaunchKernelGGL(gn_stats_kernel, dim3(256), dim3(256), 0, stream, x1, st + 2048, 65536);
    hipLaunchKernelGGL(gn_norm_act_kernel, dim3(16384), dim3(256), 0, stream,
                       x1, x1, fus_g1, fus_b1, st + 2048, 128, 4, 2);
    hipLaunchKernelGGL(lam_kernel, dim3(512), dim3(256), 0, stream,
                       x1, wcb, lam_b, lam_out);
}

// Round 3
// 1024.360 us; speedup vs baseline: 2.9296x; 1.0697x over previous
//
#include <hip/hip_runtime.h>
#include <math.h>

#define BATCH 8
#define H 128
#define W 128
#define HW 16384

typedef short bf16x8 __attribute__((ext_vector_type(8)));
typedef float f32x16 __attribute__((ext_vector_type(16)));
typedef unsigned int u32;
typedef unsigned short u16;

__device__ __forceinline__ u16 f2bf(float v) {
    u32 u = __float_as_uint(v);
    u = (u + 0x7fffu + ((u >> 16) & 1u)) >> 16;
    return (u16)u;
}

__device__ __forceinline__ void async16(void* lds, const void* g) {
    __builtin_amdgcn_global_load_lds(
        (const __attribute__((address_space(1))) u32*)g,
        (__attribute__((address_space(3))) u32*)lds, 16, 0, 0);
}

// ---------------------------------------------------------------------------
// Weight transpose: OIHW -> [I][KK][O]   (for the small fp32 direct convs)
// ---------------------------------------------------------------------------
__global__ __launch_bounds__(256) void wtrans_kernel(
    const float* __restrict__ w, float* __restrict__ wt, int O, int I, int KK)
{
    int idx = blockIdx.x * 256 + threadIdx.x;
    int total = O * I * KK;
    if (idx >= total) return;
    int k = idx % KK;
    int rest = idx / KK;
    int i = rest % I;
    int o = rest / I;
    wt[(i * KK + k) * O + o] = w[idx];
}

__global__ void wc_kernel(const float* __restrict__ fus_w2,
                          const float* __restrict__ lam_w,
                          float* __restrict__ wc)
{
    int ic = threadIdx.x;
    float s = 0.f;
    for (int oc = 0; oc < 128; ++oc) s += lam_w[oc] * fus_w2[oc * 128 + ic];
    wc[ic] = s;
}

// ---------------------------------------------------------------------------
// MFMA weight prep: OIHW fp32 -> bf16 [icblk][ocblk][half][kidx][oc64][ic8]
// ---------------------------------------------------------------------------
__global__ __launch_bounds__(256) void wprep_kernel(
    const float* __restrict__ w, u16* __restrict__ out, int Cin, int Cout)
{
    int idx = blockIdx.x * 256 + threadIdx.x;
    int total = Cin * 9 * Cout;
    if (idx >= total) return;
    int ocblks = Cout >> 6;
    int pair = idx / 9216;
    int r = idx - pair * 9216;
    int half = r / 4608;
    int r2 = r - half * 4608;
    int kidx = r2 / 512;
    int r3 = r2 - kidx * 512;
    int oc = r3 >> 3;
    int ic8 = r3 & 7;
    int icblk = pair / ocblks;
    int ocblk = pair - icblk * ocblks;
    int ic = icblk * 16 + half * 8 + ic8;
    int o = ocblk * 64 + oc;
    int ky = kidx / 3, kx = kidx - ky * 3;
    out[idx] = f2bf(w[((size_t)(o * Cin + ic) * 3 + ky) * 3 + kx]);
}

// ---------------------------------------------------------------------------
// Zero only the border pixels of a padded NHWC buffer [BATCH][130][130][C]
// ---------------------------------------------------------------------------
__global__ __launch_bounds__(256) void border_zero_kernel(u16* __restrict__ buf, int C)
{
    int chunks = 516 * C / 8;          // uint4 chunks per image border
    int idx = blockIdx.x * 256 + threadIdx.x;
    int total = BATCH * chunks;
    if (idx >= total) return;
    int b = idx / chunks;
    int r = idx - b * chunks;
    int e = r * 8;
    int pix = e / C;
    int co = e - pix * C;
    int y, x;
    if (pix < 130)      { y = 0;   x = pix; }
    else if (pix < 260) { y = 129; x = pix - 130; }
    else if (pix < 388) { y = 1 + (pix - 260); x = 0; }
    else                { y = 1 + (pix - 388); x = 129; }
    uint4 z = make_uint4(0u, 0u, 0u, 0u);
    *(uint4*)&buf[(((size_t)b * 130 + y) * 130 + x) * C + co] = z;
}

// ---------------------------------------------------------------------------
// concat(feat1,feat2) fp32 NCHW -> padded NHWC bf16 [B][130][130][256]
// ---------------------------------------------------------------------------
__global__ __launch_bounds__(256) void nhwc_concat_kernel(
    const float* __restrict__ f1, const float* __restrict__ f2,
    u16* __restrict__ out)
{
    __shared__ u16 s[32 * 256];
    int tid = threadIdx.x;
    int b = blockIdx.y;
    int xt = blockIdx.x & 3;
    int y = blockIdx.x >> 2;
    int x0 = xt * 32;
    for (int e = tid; e < 8192; e += 256) {
        int c = e >> 5, px = e & 31;
        const float* src = (c < 128) ? f1 + ((size_t)(b * 128 + c)) * HW
                                     : f2 + ((size_t)(b * 128 + c - 128)) * HW;
        s[px * 256 + c] = f2bf(src[y * W + x0 + px]);
    }
    __syncthreads();
    uint4* o4 = (uint4*)(out + (((size_t)b * 130 + y + 1) * 130 + x0 + 1) * 256);
    const uint4* s4 = (const uint4*)s;
    for (int e = tid; e < 1024; e += 256) o4[e] = s4[e];
}

// ---------------------------------------------------------------------------
// GN + act, fp32 NCHW -> padded NHWC bf16 (channel offset for concat targets)
// ---------------------------------------------------------------------------
__global__ __launch_bounds__(256) void gn_nhwc_kernel(
    const float* __restrict__ x, const float* __restrict__ gamma,
    const float* __restrict__ beta, const float* __restrict__ stats,
    u16* __restrict__ out, int Csrc, int Cdst, int coff, int Cg, int act)
{
    __shared__ u16 s[32 * 128];
    int tid = threadIdx.x;
    int b = blockIdx.y;
    int xt = blockIdx.x & 3;
    int y = blockIdx.x >> 2;
    int x0 = xt * 32;
    int n = 32 * Csrc;
    for (int e = tid; e < n; e += 256) {
        int c = e >> 5, px = e & 31;
        float v = x[((size_t)(b * Csrc + c)) * HW + y * W + x0 + px];
        int g = c / Cg;
        float mean = stats[(b * 32 + g) * 2];
        float rstd = stats[(b * 32 + g) * 2 + 1];
        float t = (v - mean) * rstd * gamma[c] + beta[c];
        t = (act == 1) ? t / (1.f + expf(-t)) : fmaxf(t, 0.f);
        s[px * Csrc + c] = f2bf(t);
    }
    __syncthreads();
    int cpp = Csrc >> 3;
    int chunks = 32 * cpp;
    for (int e = tid; e < chunks; e += 256) {
        int px = e / cpp, g = e - px * cpp;
        uint4 v = *(const uint4*)&s[px * Csrc + g * 8];
        *(uint4*)&out[(((size_t)b * 130 + y + 1) * 130 + x0 + 1 + px) * Cdst + coff + g * 8] = v;
    }
}

// ---------------------------------------------------------------------------
// MFMA implicit-GEMM 3x3 conv, pad=1.
// Block: 4 waves; wave = 128 px (4 rows x 32 cols) x 64 oc.
// Per icblk: 18 A reads cached in regs (6 rows x 3 dx) + 18 B reads, 72 MFMA.
// ---------------------------------------------------------------------------
__global__ __launch_bounds__(256, 2) void conv3x3_mfma_kernel(
    const u16* __restrict__ in_nhwc, const u16* __restrict__ wprep,
    float* __restrict__ out, int Cin, int Cout)
{
    __shared__ u16 s_in[2 * 18 * 34 * 8];   // [half][row18][col34][ic8] 19584B
    __shared__ u16 s_w[2 * 9 * 64 * 8];     // [half][kidx9][oc64][ic8] 18432B

    const int tid = threadIdx.x;
    const int b = blockIdx.y;
    const int x0 = (blockIdx.x & 3) * 32;
    const int y0 = (blockIdx.x >> 2) * 16;
    const int oc0 = blockIdx.z * 64;
    const int ocblks = Cout >> 6;
    const int icblks = Cin >> 4;

    const int lane = tid & 63;
    const int wv = tid >> 6;      // wave -> output rows wv*4 .. wv*4+3
    const int m = lane & 31;
    const int hh = lane >> 5;

    f32x16 acc[4][2];
#pragma unroll
    for (int t = 0; t < 4; ++t)
#pragma unroll
        for (int nt = 0; nt < 2; ++nt)
#pragma unroll
            for (int k = 0; k < 16; ++k) acc[t][nt][k] = 0.f;

    const u16* wsrc0 = wprep + (size_t)blockIdx.z * 9216;

    for (int it = 0; it < icblks; ++it) {
        const int ic0 = it * 16;
        __syncthreads();
        // stage input: 1224 chunks of 16B -> [half][r][col][8]
        for (int e = tid; e < 1224; e += 256) {
            int half = (e >= 612);
            int p = e - half * 612;
            int r = p / 34;
            int col = p - r * 34;
            const u16* src = in_nhwc +
                (((size_t)(b * 130 + y0 + r)) * 130 + (x0 + col)) * Cin + ic0 + half * 8;
            async16(&s_in[e * 8], src);
        }
        // stage weights: 1152 chunks of 16B
        const u16* wsrc = wsrc0 + (size_t)it * ocblks * 9216;
        for (int e = tid; e < 1152; e += 256)
            async16(&s_w[e * 8], wsrc + e * 8);
        __syncthreads();

        // register A-cache: 6 rows x 3 dx
        bf16x8 a[6][3];
#pragma unroll
        for (int s = 0; s < 6; ++s)
#pragma unroll
            for (int d = 0; d < 3; ++d)
                a[s][d] = *(const bf16x8*)&s_in[(hh * 612 + (wv * 4 + s) * 34 + m + d) * 8];

#pragma unroll
        for (int kidx = 0; kidx < 9; ++kidx) {
            const int dy = kidx / 3, dx = kidx - dy * 3;
            bf16x8 b0 = *(const bf16x8*)&s_w[(hh * 576 + kidx * 64 + m) * 8];
            bf16x8 b1 = *(const bf16x8*)&s_w[(hh * 576 + kidx * 64 + 32 + m) * 8];
#pragma unroll
            for (int t = 0; t < 4; ++t) {
                acc[t][0] = __builtin_amdgcn_mfma_f32_32x32x16_bf16(a[t + dy][dx], b0, acc[t][0], 0, 0, 0);
                acc[t][1] = __builtin_amdgcn_mfma_f32_32x32x16_bf16(a[t + dy][dx], b1, acc[t][1], 0, 0, 0);
            }
        }
    }

    // epilogue: x offset = g*8 + hh*4 + (reg&3), col = oc
#pragma unroll
    for (int t = 0; t < 4; ++t) {
        int y = y0 + wv * 4 + t;
#pragma unroll
        for (int nt = 0; nt < 2; ++nt) {
            int oc = oc0 + nt * 32 + m;
            float* op = out + ((size_t)(b * Cout + oc)) * HW + y * W + x0;
#pragma unroll
            for (int g = 0; g < 4; ++g) {
                float4 v = make_float4(acc[t][nt][g * 4 + 0], acc[t][nt][g * 4 + 1],
                                       acc[t][nt][g * 4 + 2], acc[t][nt][g * 4 + 3]);
                *(float4*)(op + g * 8 + hh * 4) = v;
            }
        }
    }
}

// ---------------------------------------------------------------------------
// Direct fp32 3x3 conv (kept for tiny conv3: Cout=3)
// ---------------------------------------------------------------------------
#define CK 8
__global__ __launch_bounds__(256) void conv3x3_kernel(
    const float* __restrict__ in0, int C0,
    const float* __restrict__ in1, int C1,
    const float* __restrict__ wt,
    const float* __restrict__ bias,
    float* __restrict__ out, int Cout)
{
    __shared__ alignas(16) float s_in[CK][6][36];
    __shared__ alignas(16) float s_w[CK][9][32];

    int b = blockIdx.y;
    int octile = blockIdx.z * 32;
    int tile = blockIdx.x;
    int x0 = (tile & 3) * 32;
    int y0 = (tile >> 2) * 4;
    int tid = threadIdx.x;
    int oc4 = (tid & 7) * 4;
    int pg = tid >> 3;
    int tyy = pg >> 3;
    int txx = (pg & 7) * 4;
    int Cin = C0 + C1;

    float acc[4][4];
#pragma unroll
    for (int j = 0; j < 4; ++j)
#pragma unroll
        for (int o = 0; o < 4; ++o) acc[j][o] = 0.f;

    for (int cb = 0; cb < Cin; cb += CK) {
        __syncthreads();
        for (int e = tid; e < CK * 6 * 34; e += 256) {
            int cc = e / 204;
            int rem = e - cc * 204;
            int r = rem / 34;
            int col = rem - r * 34;
            int gy = y0 + r - 1;
            int gx = x0 + col - 1;
            float v = 0.f;
            if (gy >= 0 && gy < H && gx >= 0 && gx < W) {
                int c = cb + cc;
                v = (c < C0) ? in0[((size_t)b * C0 + c) * HW + gy * W + gx]
                             : in1[((size_t)b * C1 + (c - C0)) * HW + gy * W + gx];
            }
            s_in[cc][r][col] = v;
        }
        for (int e = tid; e < CK * 9 * 32; e += 256) {
            int cc = e / 288;
            int rem = e - cc * 288;
            int k = rem / 32;
            int oc = rem - k * 32;
            int gc = octile + oc;
            s_w[cc][k][oc] = (gc < Cout) ? wt[((size_t)(cb + cc) * 9 + k) * Cout + gc] : 0.f;
        }
        __syncthreads();

#pragma unroll
        for (int cc = 0; cc < CK; ++cc) {
            float xin[3][6];
#pragma unroll
            for (int i = 0; i < 3; ++i) {
                const float4 v4 = *(const float4*)&s_in[cc][tyy + i][txx];
                const float2 v2 = *(const float2*)&s_in[cc][tyy + i][txx + 4];
                xin[i][0] = v4.x; xin[i][1] = v4.y; xin[i][2] = v4.z; xin[i][3] = v4.w;
                xin[i][4] = v2.x; xin[i][5] = v2.y;
            }
#pragma unroll
            for (int ky = 0; ky < 3; ++ky)
#pragma unroll
                for (int kx = 0; kx < 3; ++kx) {
                    const float4 wvv = *(const float4*)&s_w[cc][ky * 3 + kx][oc4];
#pragma unroll
                    for (int j = 0; j < 4; ++j) {
                        float xv = xin[ky][j + kx];
                        acc[j][0] += wvv.x * xv;
                        acc[j][1] += wvv.y * xv;
                        acc[j][2] += wvv.z * xv;
                        acc[j][3] += wvv.w * xv;
                    }
                }
        }
    }

    int ox = x0 + txx;
    int oy = y0 + tyy;
#pragma unroll
    for (int o = 0; o < 4; ++o) {
        int oc = octile + oc4 + o;
        if (oc < Cout) {
            float bv = bias ? bias[oc] : 0.f;
            float4 vv = make_float4(acc[0][o] + bv, acc[1][o] + bv,
                                    acc[2][o] + bv, acc[3][o] + bv);
            *(float4*)&out[((size_t)b * Cout + oc) * HW + oy * W + ox] = vv;
        }
    }
}

// ---------------------------------------------------------------------------
__global__ __launch_bounds__(256) void gn_stats_kernel(
    const float* __restrict__ x, float* __restrict__ stats, int CgHW)
{
    int bg = blockIdx.x;
    const float4* p4 = (const float4*)(x + (size_t)bg * CgHW);
    int n4 = CgHW / 4;
    float s1 = 0.f, s2 = 0.f;
    for (int i = threadIdx.x; i < n4; i += 256) {
        float4 v = p4[i];
        s1 += v.x + v.y + v.z + v.w;
        s2 += v.x * v.x + v.y * v.y + v.z * v.z + v.w * v.w;
    }
    for (int off = 32; off > 0; off >>= 1) {
        s1 += __shfl_down(s1, off);
        s2 += __shfl_down(s2, off);
    }
    __shared__ float r1[4], r2[4];
    int wid = threadIdx.x >> 6;
    if ((threadIdx.x & 63) == 0) { r1[wid] = s1; r2[wid] = s2; }
    __syncthreads();
    if (threadIdx.x == 0) {
        float a = r1[0] + r1[1] + r1[2] + r1[3];
        float q = r2[0] + r2[1] + r2[2] + r2[3];
        float inv_n = 1.0f / (float)CgHW;
        float mean = a * inv_n;
        float var = q * inv_n - mean * mean;
        stats[bg * 2] = mean;
        stats[bg * 2 + 1] = rsqrtf(var + 1e-5f);
    }
}

__global__ __launch_bounds__(256) void gn_norm_act_kernel(
    const float* __restrict__ x, float* __restrict__ y,
    const float* __restrict__ gamma, const float* __restrict__ beta,
    const float* __restrict__ stats, int C, int Cg, int act)
{
    int idx = blockIdx.x * 256 + threadIdx.x;
    int total4 = BATCH * C * HW / 4;
    if (idx >= total4) return;
    int e = idx * 4;
    int c = (e / HW) % C;
    int b = e / (C * HW);
    int g = c / Cg;
    float mean = stats[(b * 32 + g) * 2];
    float rstd = stats[(b * 32 + g) * 2 + 1];
    float sc = rstd * gamma[c];
    float sh = beta[c] - mean * sc;
    float4 v = ((const float4*)x)[idx];
    float r[4] = {v.x, v.y, v.z, v.w};
#pragma unroll
    for (int i = 0; i < 4; ++i) {
        float t = r[i] * sc + sh;
        if (act == 1) t = t / (1.f + expf(-t));
        else if (act == 2) t = fmaxf(t, 0.f);
        r[i] = t;
    }
    ((float4*)y)[idx] = make_float4(r[0], r[1], r[2], r[3]);
}

// ---------------------------------------------------------------------------
__global__ __launch_bounds__(256) void warp_kernel(
    const float* __restrict__ feat2, const float* __restrict__ pred,
    float* __restrict__ aligned, float* __restrict__ flow_out)
{
    int idx = blockIdx.x * 256 + threadIdx.x;
    int b = idx / HW;
    int p = idx - b * HW;
    int y = p >> 7;
    int x = p & 127;
    const float* predb = pred + (size_t)b * 3 * HW;
    float fx = predb[p];
    float fy = predb[HW + p];
    float validity = 1.f / (1.f + expf(-predb[2 * HW + p]));
    flow_out[(size_t)(b * 2) * HW + p] = fx;
    flow_out[(size_t)(b * 2 + 1) * HW + p] = fy;

    float px = (float)x + fx;
    float py = (float)y + fy;
    float x0f = floorf(px), y0f = floorf(py);
    float wx = px - x0f, wy = py - y0f;
    int xi0 = (int)x0f, yi0 = (int)y0f;
    float wgt[2][2] = {{(1.f - wx) * (1.f - wy), wx * (1.f - wy)},
                       {(1.f - wx) * wy, wx * wy}};
    float vm[2][2];
    int offc[2][2];
#pragma unroll
    for (int yy = 0; yy < 2; ++yy)
#pragma unroll
        for (int xx = 0; xx < 2; ++xx) {
            int xi = xi0 + xx, yi = yi0 + yy;
            bool ok = (xi >= 0) && (xi <= W - 1) && (yi >= 0) && (yi <= H - 1);
            vm[yy][xx] = ok ? wgt[yy][xx] : 0.f;
            int xc = min(max(xi, 0), W - 1);
            int yc = min(max(yi, 0), H - 1);
            offc[yy][xx] = yc * W + xc;
        }
    const float* f2b = feat2 + (size_t)b * 128 * HW;
    float* outb = aligned + (size_t)b * 128 * HW;
    for (int c = 0; c < 128; ++c) {
        const float* f2c = f2b + (size_t)c * HW;
        float val = f2c[offc[0][0]] * vm[0][0] + f2c[offc[0][1]] * vm[0][1] +
                    f2c[offc[1][0]] * vm[1][0] + f2c[offc[1][1]] * vm[1][1];
        outb[(size_t)c * HW + p] = val * validity;
    }
}

// ---------------------------------------------------------------------------
// Cost volume. 16x16 px tile; aligned tile staged as bf16 [24*24][8ch];
// acc[81] fp32 in regs (launch_bounds(256,1) -> no spill); 16 chunks of 8 ch.
// ---------------------------------------------------------------------------
__global__ __launch_bounds__(256, 1) void costvol_kernel(
    const float* __restrict__ feat1, const float* __restrict__ aligned,
    float* __restrict__ cv)
{
    __shared__ u16 s_al[576 * 8];   // [r*24+col][8ch] bf16, 9216B
    int b = blockIdx.y;
    int bx = blockIdx.x & 7, by = blockIdx.x >> 3;
    int tid = threadIdx.x;
    int ly = tid >> 4, lx = tid & 15;
    int gy = by * 16 + ly, gx = bx * 16 + lx;

    float acc[81];
#pragma unroll
    for (int k = 0; k < 81; ++k) acc[k] = 0.f;

    const float* f1b = feat1 + (size_t)b * 128 * HW;
    const float* alb = aligned + (size_t)b * 128 * HW;

    for (int c0 = 0; c0 < 128; c0 += 8) {
        __syncthreads();
        // stage: each e = one pixel of the 24x24 halo tile, 8 channels packed
        for (int e = tid; e < 576; e += 256) {
            int r = e / 24;
            int col = e - r * 24;
            int ay = by * 16 + r - 4, ax = bx * 16 + col - 4;
            bf16x8 pk;
            if (ay >= 0 && ay < H && ax >= 0 && ax < W) {
                const float* src = alb + (size_t)c0 * HW + ay * W + ax;
#pragma unroll
                for (int cc = 0; cc < 8; ++cc)
                    pk[cc] = (short)f2bf(src[(size_t)cc * HW]);
            } else {
#pragma unroll
                for (int cc = 0; cc < 8; ++cc) pk[cc] = 0;
            }
            *(bf16x8*)&s_al[e * 8] = pk;
        }
        __syncthreads();

        float f1v[8];
#pragma unroll
        for (int cc = 0; cc < 8; ++cc)
            f1v[cc] = f1b[(size_t)(c0 + cc) * HW + gy * W + gx];

#pragma unroll
        for (int dy = 0; dy < 9; ++dy) {
#pragma unroll
            for (int dx = 0; dx < 9; ++dx) {
                union { bf16x8 v; u32 w[4]; } U;
                U.v = *(const bf16x8*)&s_al[((ly + dy) * 24 + lx + dx) * 8];
                float s = acc[dy * 9 + dx];
#pragma unroll
                for (int q = 0; q < 4; ++q) {
                    float lo = __uint_as_float(U.w[q] << 16);
                    float hi = __uint_as_float(U.w[q] & 0xffff0000u);
                    s += lo * f1v[2 * q];
                    s += hi * f1v[2 * q + 1];
                }
                acc[dy * 9 + dx] = s;
            }
        }
    }
    const float scale = 1.f / 128.f;
    float* cvb = cv + (size_t)b * 81 * HW + gy * W + gx;
#pragma unroll
    for (int k = 0; k < 81; ++k) cvb[(size_t)k * HW] = acc[k] * scale;
}

// ---------------------------------------------------------------------------
__global__ __launch_bounds__(256) void conv1x1_kernel(
    const float* __restrict__ inA, const float* __restrict__ inB,
    const float* __restrict__ wt, float* __restrict__ out, int Cin)
{
    __shared__ alignas(16) float s_w[128 * 64];
    int tid = threadIdx.x;
    for (int e = tid; e < Cin * 64; e += 256) s_w[e] = wt[e];
    __syncthreads();
    int idx = blockIdx.x * 256 + tid;
    int b = idx / HW;
    int p = idx - b * HW;
    float acc[64];
#pragma unroll
    for (int o = 0; o < 64; ++o) acc[o] = 0.f;
    const float* Ab = inA + (size_t)b * Cin * HW + p;
    const float* Bb = inB ? inB + (size_t)b * Cin * HW + p : nullptr;
    for (int ic = 0; ic < Cin; ++ic) {
        float xv = Ab[(size_t)ic * HW];
        if (inB) xv = fabsf(xv - Bb[(size_t)ic * HW]);
        const float* wr = &s_w[ic * 64];
#pragma unroll
        for (int o4 = 0; o4 < 64; o4 += 4) {
            const float4 wvv = *(const float4*)&wr[o4];
            acc[o4 + 0] += wvv.x * xv;
            acc[o4 + 1] += wvv.y * xv;
            acc[o4 + 2] += wvv.z * xv;
            acc[o4 + 3] += wvv.w * xv;
        }
    }
    float* ob = out + (size_t)b * 64 * HW + p;
#pragma unroll
    for (int o = 0; o < 64; ++o) ob[(size_t)o * HW] = acc[o];
}

__global__ __launch_bounds__(256) void lam_kernel(
    const float* __restrict__ f1, const float* __restrict__ wc,
    const float* __restrict__ lam_b, float* __restrict__ out)
{
    __shared__ float s_w[128];
    int tid = threadIdx.x;
    if (tid < 128) s_w[tid] = wc[tid];
    __syncthreads();
    int idx = blockIdx.x * 256 + tid;
    int b = idx / HW;
    int p = idx - b * HW;
    const float* fb = f1 + (size_t)b * 128 * HW + p;
    float acc = 0.f;
#pragma unroll 4
    for (int ic = 0; ic < 128; ++ic) acc += s_w[ic] * fb[(size_t)ic * HW];
    acc += lam_b[0];
    out[idx] = 1.f / (1.f + expf(-acc));
}

// ---------------------------------------------------------------------------
extern "C" void kernel_launch(void* const* d_in, const int* in_sizes, int n_in,
                              void* d_out, int out_size, void* d_ws, size_t ws_size,
                              hipStream_t stream)
{
    const float* feat1     = (const float*)d_in[0];
    const float* feat2     = (const float*)d_in[1];
    const float* off_w1    = (const float*)d_in[2];
    const float* off_g1    = (const float*)d_in[3];
    const float* off_b1    = (const float*)d_in[4];
    const float* off_w2    = (const float*)d_in[5];
    const float* off_g2    = (const float*)d_in[6];
    const float* off_b2    = (const float*)d_in[7];
    const float* off_w3    = (const float*)d_in[8];
    const float* off_bias3 = (const float*)d_in[9];
    const float* corr_w    = (const float*)d_in[10];
    const float* corr_g    = (const float*)d_in[11];
    const float* corr_b    = (const float*)d_in[12];
    const float* diff_w    = (const float*)d_in[13];
    const float* diff_g    = (const float*)d_in[14];
    const float* diff_b    = (const float*)d_in[15];
    const float* fus_w1    = (const float*)d_in[16];
    const float* fus_g1    = (const float*)d_in[17];
    const float* fus_b1    = (const float*)d_in[18];
    const float* fus_w2    = (const float*)d_in[19];
    const float* lam_w     = (const float*)d_in[20];
    const float* lam_b     = (const float*)d_in[21];

    float* ws = (float*)d_ws;
    float* x1  = ws;                      // 16,777,216  conv1 out / fus1 out
    float* x2  = ws + 16777216;           //  8,388,608  conv2 out / de
    float* Rcv = ws + 25165824;           // 10,616,832  p2 -> cv -> pf
    float* Rp1 = ws + 35782656;           // 17,305,600  p1 -> (ce, pred)
    u16*  wp1u = (u16*)(ws + 53088256);
    u16*  wp2u = (u16*)(ws + 53235712);
    u16*  wpfu = (u16*)(ws + 53272576);
    float* wT3 = ws + 53346304;
    float* wTc = ws + 53348032;
    float* wTd = ws + 53353216;
    float* wcb = ws + 53361408;
    float* st  = ws + 53361536;

    u16* p1u = (u16*)Rp1;                 // [8][130][130][256] bf16
    u16* p2u = (u16*)Rcv;                 // [8][130][130][128] bf16
    u16* pfu = (u16*)Rcv;                 // [8][130][130][128] bf16 (after cv dead)
    float* cv = Rcv;
    float* ce = Rp1;                      // after p1 dead
    float* pred = Rp1 + 8388608;          // after p1 dead

    float* aligned  = (float*)d_out;
    float* flow_out = aligned + 16777216;
    float* lam_out  = aligned + 17039360;

    // ---- weight prep ----
    auto T = [&](const float* w, float* wt, int O, int I, int KK) {
        int total = O * I * KK;
        hipLaunchKernelGGL(wtrans_kernel, dim3((total + 255) / 256), dim3(256), 0, stream,
                           w, wt, O, I, KK);
    };
    T(off_w3, wT3, 3, 64, 9);
    T(corr_w, wTc, 64, 81, 1);
    T(diff_w, wTd, 64, 128, 1);
    hipLaunchKernelGGL(wc_kernel, dim3(1), dim3(128), 0, stream, fus_w2, lam_w, wcb);
    hipLaunchKernelGGL(wprep_kernel, dim3(1152), dim3(256), 0, stream, off_w1, wp1u, 256, 128);
    hipLaunchKernelGGL(wprep_kernel, dim3(288), dim3(256), 0, stream, off_w2, wp2u, 128, 64);
    hipLaunchKernelGGL(wprep_kernel, dim3(576), dim3(256), 0, stream, fus_w1, wpfu, 128, 128);

    // border-only zero of padded NHWC buffers
    hipLaunchKernelGGL(border_zero_kernel, dim3(516), dim3(256), 0, stream, p1u, 256);
    hipLaunchKernelGGL(border_zero_kernel, dim3(258), dim3(256), 0, stream, p2u, 128);

    // ---- offset net ----
    hipLaunchKernelGGL(nhwc_concat_kernel, dim3(512, 8), dim3(256), 0, stream,
                       feat1, feat2, p1u);
    hipLaunchKernelGGL(conv3x3_mfma_kernel, dim3(32, 8, 2), dim3(256), 0, stream,
                       p1u, wp1u, x1, 256, 128);
    hipLaunchKernelGGL(gn_stats_kernel, dim3(256), dim3(256), 0, stream, x1, st, 65536);
    hipLaunchKernelGGL(gn_nhwc_kernel, dim3(512, 8), dim3(256), 0, stream,
                       x1, off_g1, off_b1, st, p2u, 128, 128, 0, 4, 1);
    hipLaunchKernelGGL(conv3x3_mfma_kernel, dim3(32, 8, 1), dim3(256), 0, stream,
                       p2u, wp2u, x2, 128, 64);
    hipLaunchKernelGGL(gn_stats_kernel, dim3(256), dim3(256), 0, stream, x2, st + 512, 32768);
    hipLaunchKernelGGL(gn_norm_act_kernel, dim3(8192), dim3(256), 0, stream,
                       x2, x2, off_g2, off_b2, st + 512, 64, 2, 1);
    hipLaunchKernelGGL(conv3x3_kernel, dim3(128, 8, 1), dim3(256), 0, stream,
                       x2, 64, (const float*)nullptr, 0, wT3, off_bias3, pred, 3);

    // ---- warp + cost volume ----
    hipLaunchKernelGGL(warp_kernel, dim3(512), dim3(256), 0, stream,
                       feat2, pred, aligned, flow_out);
    hipLaunchKernelGGL(costvol_kernel, dim3(64, 8), dim3(256), 0, stream,
                       feat1, aligned, cv);

    // ---- corr branch ----
    hipLaunchKernelGGL(conv1x1_kernel, dim3(512), dim3(256), 0, stream,
                       cv, (const float*)nullptr, wTc, ce, 81);
    hipLaunchKernelGGL(gn_stats_kernel, dim3(256), dim3(256), 0, stream, ce, st + 1024, 32768);
    hipLaunchKernelGGL(border_zero_kernel, dim3(258), dim3(256), 0, stream, pfu, 128);
    hipLaunchKernelGGL(gn_nhwc_kernel, dim3(512, 8), dim3(256), 0, stream,
                       ce, corr_g, corr_b, st + 1024, pfu, 64, 128, 0, 2, 2);

    // ---- diff branch (de in x2) ----
    hipLaunchKernelGGL(conv1x1_kernel, dim3(512), dim3(256), 0, stream,
                       feat1, aligned, wTd, x2, 128);
    hipLaunchKernelGGL(gn_stats_kernel, dim3(256), dim3(256), 0, stream, x2, st + 1536, 32768);
    hipLaunchKernelGGL(gn_nhwc_kernel, dim3(512, 8), dim3(256), 0, stream,
                       x2, diff_g, diff_b, st + 1536, pfu, 64, 128, 64, 2, 2);

    // ---- fusion ----
    hipLaunchKernelGGL(conv3x3_mfma_kernel, dim3(32, 8, 2), dim3(256), 0, stream,
                       pfu, wpfu, x1, 128, 128);
    hipLaunchKernelGGL(gn_stats_kernel, dim3(256), dim3(256), 0, stream, x1, st + 2048, 65536);
    hipLaunchKernelGGL(gn_norm_act_kernel, dim3(16384), dim3(256), 0, stream,
                       x1, x1, fus_g1, fus_b1, st + 2048, 128, 4, 2);
    hipLaunchKernelGGL(lam_kernel, dim3(512), dim3(256), 0, stream,
                       x1, wcb, lam_b, lam_out);
}